// Round 1
// baseline (302.164 us; speedup 1.0000x reference)
//
#include <hip/hip_runtime.h>
#include <stdint.h>

#define Bb 2
#define Ss 2048
#define Ee 1024
#define Hh 16
#define Dd 64

typedef __bf16 bf16;
typedef __attribute__((ext_vector_type(8))) __bf16 bf16x8;
typedef __attribute__((ext_vector_type(4))) __bf16 bf16x4;
typedef __attribute__((ext_vector_type(4))) float f32x4;

#define MB (1u << 20)
// workspace layout (bf16 regions), total 64 MB
#define OFF_XQ 0u
#define OFF_XK (8u * MB)
#define OFF_XV (16u * MB)
#define OFF_WQ (24u * MB)
#define OFF_WK (26u * MB)
#define OFF_WV (28u * MB)
#define OFF_WO (30u * MB)
#define OFF_Q  (32u * MB)   // [B,H,S,D], prescaled by 1/8 via Wq,bq
#define OFF_K  (40u * MB)   // [B,H,S,D]
#define OFF_VT (48u * MB)   // [B,H,D,S]  (transposed V)
#define OFF_AO (56u * MB)   // [B*S, E] attention output

__device__ __forceinline__ void gll16(const void* g, void* lds) {
  __builtin_amdgcn_global_load_lds(
      (const __attribute__((address_space(1))) void*)g,
      (__attribute__((address_space(3))) void*)lds, 16, 0, 0);
}

// ---------------- convert fp32 -> bf16 (Wq scaled by 1/8) ----------------
__global__ __launch_bounds__(256) void convert_kernel(
    const float* __restrict__ q, const float* __restrict__ k, const float* __restrict__ v,
    const float* __restrict__ wq, const float* __restrict__ wk, const float* __restrict__ wv,
    const float* __restrict__ wo, char* __restrict__ ws)
{
  const unsigned i = blockIdx.x * 256u + threadIdx.x;  // float4 units, 4194304 total
  const float* src;
  bf16* dst;
  float scale = 1.0f;
  if (i < 3145728u) {                      // queries/keys/values: 1M float4 each
    const unsigned a = i >> 20, j = i & 1048575u;
    src = (a == 0 ? q : a == 1 ? k : v) + (size_t)j * 4;
    dst = (bf16*)(ws + (size_t)a * (8u * MB)) + (size_t)j * 4;
  } else {                                 // Wq,Wk,Wv,Wo: 256K float4 each
    const unsigned i2 = i - 3145728u;
    const unsigned a = i2 >> 18, j = i2 & 262143u;
    src = (a == 0 ? wq : a == 1 ? wk : a == 2 ? wv : wo) + (size_t)j * 4;
    dst = (bf16*)(ws + OFF_WQ + (size_t)a * (2u * MB)) + (size_t)j * 4;
    if (a == 0) scale = 0.125f;            // fold 1/sqrt(D) into Wq
  }
  const float4 f = *(const float4*)src;
  bf16x4 o;
  o[0] = (bf16)(f.x * scale);
  o[1] = (bf16)(f.y * scale);
  o[2] = (bf16)(f.z * scale);
  o[3] = (bf16)(f.w * scale);
  *(bf16x4*)dst = o;
}

// ---------------- shared 128x128x(K) bf16 GEMM body (C = A * W^T) ----------------
// A: [M x 1024] row-major bf16; W: [N x 1024] row-major bf16 (i.e. B^T layout).
// LDS tiles 128x64 bf16 (128B rows), XOR-swizzled 16B chunks: chunk ^= (row&7).
__device__ __forceinline__ void gemm128_body(
    const bf16* __restrict__ A, const bf16* __restrict__ W,
    char* smem, int m0, int n0, int t, f32x4 (&acc)[4][4])
{
  char* As = smem;
  char* Bs = smem + 16384;
  const int lane = t & 63;
  const int wid = t >> 6;
  const int wm = (wid >> 1) << 6;   // wave sub-tile origin
  const int wn = (wid & 1) << 6;
  for (int kt = 0; kt < 1024; kt += 64) {
    __syncthreads();
#pragma unroll
    for (int i = 0; i < 4; ++i) {
      const int L = i * 4096 + t * 16;        // linear LDS byte offset
      const int r = L >> 7;                   // tile row (128B rows)
      const int c = ((L >> 4) & 7) ^ (r & 7); // logical 16B chunk (pre-swizzled source)
      gll16(A + (size_t)(m0 + r) * 1024 + kt + c * 8, As + i * 4096 + wid * 1024);
      gll16(W + (size_t)(n0 + r) * 1024 + kt + c * 8, Bs + i * 4096 + wid * 1024);
    }
    __syncthreads();
#pragma unroll
    for (int ks = 0; ks < 2; ++ks) {
      bf16x8 af[4], bff[4];
#pragma unroll
      for (int mi = 0; mi < 4; ++mi) {
        const int r = wm + mi * 16 + (lane & 15);
        const int c = (ks * 4 + (lane >> 4)) ^ (r & 7);
        af[mi] = *(const bf16x8*)(As + r * 128 + c * 16);
      }
#pragma unroll
      for (int ni = 0; ni < 4; ++ni) {
        const int r = wn + ni * 16 + (lane & 15);
        const int c = (ks * 4 + (lane >> 4)) ^ (r & 7);
        bff[ni] = *(const bf16x8*)(Bs + r * 128 + c * 16);
      }
#pragma unroll
      for (int mi = 0; mi < 4; ++mi)
#pragma unroll
        for (int ni = 0; ni < 4; ++ni)
          acc[mi][ni] = __builtin_amdgcn_mfma_f32_16x16x32_bf16(af[mi], bff[ni], acc[mi][ni], 0, 0, 0);
    }
  }
}

// ---------------- fused Q/K/V projection (grid.z selects q/k/v) ----------------
__global__ __launch_bounds__(256) void proj_gemm(
    char* __restrict__ ws, const float* __restrict__ bq,
    const float* __restrict__ bk, const float* __restrict__ bv)
{
  __shared__ __align__(16) char smem[32768];
  const int zi = blockIdx.z;
  const bf16* A = (const bf16*)(ws + (zi == 0 ? OFF_XQ : zi == 1 ? OFF_XK : OFF_XV));
  const bf16* W = (const bf16*)(ws + (zi == 0 ? OFF_WQ : zi == 1 ? OFF_WK : OFF_WV));
  const float* bias = zi == 0 ? bq : zi == 1 ? bk : bv;
  bf16* outp = (bf16*)(ws + (zi == 0 ? OFF_Q : zi == 1 ? OFF_K : OFF_VT));
  const float bscale = (zi == 0) ? 0.125f : 1.0f;
  const int t = threadIdx.x;
  const int m0 = blockIdx.y * 128, n0 = blockIdx.x * 128;
  f32x4 acc[4][4] = {};
  gemm128_body(A, W, smem, m0, n0, t, acc);
  const int lane = t & 63, wid = t >> 6;
  const int wm = (wid >> 1) << 6, wn = (wid & 1) << 6;
  const int cl = lane & 15, rl = lane >> 4;
#pragma unroll
  for (int ni = 0; ni < 4; ++ni) {
    const int col = n0 + wn + ni * 16 + cl;
    const float bvv = bias[col] * bscale;
    const int h = col >> 6, d = col & 63;
#pragma unroll
    for (int mi = 0; mi < 4; ++mi) {
#pragma unroll
      for (int r2 = 0; r2 < 4; ++r2) {
        const int row = m0 + wm + mi * 16 + rl * 4 + r2;  // token index
        const int b = row >> 11, s = row & 2047;
        const float val = acc[mi][ni][r2] + bvv;
        if (zi == 2) {  // V stored transposed: [B,H,D,S]
          outp[((size_t)((b * Hh + h) * Dd + d) * Ss) + s] = (bf16)val;
        } else {        // Q/K: [B,H,S,D]
          outp[((size_t)((b * Hh + h) * Ss + s) * Dd) + d] = (bf16)val;
        }
      }
    }
  }
}

// ---------------- attention: softmax(sigmoid(QK^T/8)) @ V ----------------
// grid: (S/128, B*H). 4 waves x 32 q-rows. No running max needed: sigmoid in (0,1).
__global__ __launch_bounds__(256) void attn_kernel(char* __restrict__ ws,
                                                   const int* __restrict__ indicator)
{
  __shared__ __align__(16) char smem[81920];
  char* Qs  = smem;            // [128][64] bf16, 128B rows, swz (r&7)
  char* Ks  = smem + 16384;    // [128][64]
  char* Vts = smem + 32768;    // [64][128] bf16, 256B rows, swz (r&15)
  char* Ps  = smem + 49152;    // [128][128] bf16, 256B rows, swz (r&15)
  const int t = threadIdx.x, lane = t & 63, wid = t >> 6;
  const int bh = blockIdx.y;
  const int q0 = blockIdx.x * 128;
  const bf16* Qg  = (const bf16*)(ws + OFF_Q)  + (size_t)bh * Ss * Dd;
  const bf16* Kg  = (const bf16*)(ws + OFF_K)  + (size_t)bh * Ss * Dd;
  const bf16* Vtg = (const bf16*)(ws + OFF_VT) + (size_t)bh * Ss * Dd;
  bf16* AO = (bf16*)(ws + OFF_AO);
  const int ind = *indicator;
  // w = sigmoid(sgn*s); e = exp2(c1*s), sig = 1/(1+e); c1 = -sgn*log2(e)
  const float c1 = (ind != 0) ? 1.44269504f : -1.44269504f;

  // stage Q tile [128 q][64 d]
#pragma unroll
  for (int i = 0; i < 4; ++i) {
    const int L = i * 4096 + t * 16;
    const int r = L >> 7;
    const int c = ((L >> 4) & 7) ^ (r & 7);
    gll16(Qg + (size_t)(q0 + r) * Dd + c * 8, Qs + i * 4096 + wid * 1024);
  }
  __syncthreads();
  const int wq = wid * 32;  // this wave's q-row origin within tile
  bf16x8 qf[2][2];
#pragma unroll
  for (int mi = 0; mi < 2; ++mi)
#pragma unroll
    for (int ks = 0; ks < 2; ++ks) {
      const int r = wq + mi * 16 + (lane & 15);
      const int c = (ks * 4 + (lane >> 4)) ^ (r & 7);
      qf[mi][ks] = *(const bf16x8*)(Qs + r * 128 + c * 16);
    }

  f32x4 acc_o[2][4] = {};
  float ps[2][4] = {};  // row-sum partials, row = wq+mi*16+(lane>>4)*4+r

  for (int kt = 0; kt < Ss; kt += 128) {
    __syncthreads();
    // stage K tile [128 kv][64 d]
#pragma unroll
    for (int i = 0; i < 4; ++i) {
      const int L = i * 4096 + t * 16;
      const int r = L >> 7;
      const int c = ((L >> 4) & 7) ^ (r & 7);
      gll16(Kg + (size_t)(kt + r) * Dd + c * 8, Ks + i * 4096 + wid * 1024);
    }
    // stage Vt tile [64 d][128 kv]
#pragma unroll
    for (int i = 0; i < 4; ++i) {
      const int L = i * 4096 + t * 16;
      const int r = L >> 8;
      const int c = ((L >> 4) & 15) ^ (r & 15);
      gll16(Vtg + (size_t)r * Ss + kt + c * 8, Vts + i * 4096 + wid * 1024);
    }
    __syncthreads();
    // S = Q K^T  (Q prescaled by 1/8)
    f32x4 acc_s[2][8] = {};
#pragma unroll
    for (int ks = 0; ks < 2; ++ks) {
      bf16x8 kf[8];
#pragma unroll
      for (int ni = 0; ni < 8; ++ni) {
        const int r = ni * 16 + (lane & 15);
        const int c = (ks * 4 + (lane >> 4)) ^ (r & 7);
        kf[ni] = *(const bf16x8*)(Ks + r * 128 + c * 16);
      }
#pragma unroll
      for (int mi = 0; mi < 2; ++mi)
#pragma unroll
        for (int ni = 0; ni < 8; ++ni)
          acc_s[mi][ni] = __builtin_amdgcn_mfma_f32_16x16x32_bf16(qf[mi][ks], kf[ni], acc_s[mi][ni], 0, 0, 0);
    }
    // P = exp(sigmoid(+/- s)); accumulate row-sums; scatter P to LDS (own rows only)
#pragma unroll
    for (int mi = 0; mi < 2; ++mi)
#pragma unroll
      for (int ni = 0; ni < 8; ++ni)
#pragma unroll
        for (int r2 = 0; r2 < 4; ++r2) {
          const float sv = acc_s[mi][ni][r2];
          const float e = __builtin_amdgcn_exp2f(sv * c1);
          const float sig = __builtin_amdgcn_rcpf(1.0f + e);
          const float p = __builtin_amdgcn_exp2f(sig * 1.44269504f);
          ps[mi][r2] += p;
          const int row = wq + mi * 16 + (lane >> 4) * 4 + r2;
          const int col = ni * 16 + (lane & 15);
          const int addr = row * 256 + ((((col >> 3) << 4)) ^ ((row & 15) << 4)) + (col & 7) * 2;
          *(bf16*)(Ps + addr) = (bf16)p;
        }
    // O += P V   (A = P rows of this wave, B = Vt)
#pragma unroll
    for (int ks = 0; ks < 4; ++ks) {
      bf16x8 pf[2], vf[4];
#pragma unroll
      for (int mi = 0; mi < 2; ++mi) {
        const int r = wq + mi * 16 + (lane & 15);
        const int c = (ks * 4 + (lane >> 4)) ^ (r & 15);
        pf[mi] = *(const bf16x8*)(Ps + r * 256 + c * 16);
      }
#pragma unroll
      for (int ni = 0; ni < 4; ++ni) {
        const int r = ni * 16 + (lane & 15);
        const int c = (ks * 4 + (lane >> 4)) ^ (r & 15);
        vf[ni] = *(const bf16x8*)(Vts + r * 256 + c * 16);
      }
#pragma unroll
      for (int mi = 0; mi < 2; ++mi)
#pragma unroll
        for (int ni = 0; ni < 4; ++ni)
          acc_o[mi][ni] = __builtin_amdgcn_mfma_f32_16x16x32_bf16(pf[mi], vf[ni], acc_o[mi][ni], 0, 0, 0);
    }
  }
  // reduce row-sums across the 16 lanes sharing each row group; invert
#pragma unroll
  for (int mi = 0; mi < 2; ++mi)
#pragma unroll
    for (int r2 = 0; r2 < 4; ++r2) {
      float v = ps[mi][r2];
      v += __shfl_xor(v, 1);
      v += __shfl_xor(v, 2);
      v += __shfl_xor(v, 4);
      v += __shfl_xor(v, 8);
      ps[mi][r2] = __builtin_amdgcn_rcpf(v);
    }
  const int b = bh >> 4, h = bh & 15;
#pragma unroll
  for (int mi = 0; mi < 2; ++mi)
#pragma unroll
    for (int ni = 0; ni < 4; ++ni)
#pragma unroll
      for (int r2 = 0; r2 < 4; ++r2) {
        const int qrow = q0 + wq + mi * 16 + (lane >> 4) * 4 + r2;
        const int dd = ni * 16 + (lane & 15);
        const float val = acc_o[mi][ni][r2] * ps[mi][r2];
        AO[((size_t)(b * Ss + qrow) << 10) + h * 64 + dd] = (bf16)val;
      }
}

// ---------------- output projection: d_out = AO @ Wo^T + bo (fp32 out) ----------------
__global__ __launch_bounds__(256) void out_gemm(char* __restrict__ ws,
                                                const float* __restrict__ bo,
                                                float* __restrict__ outp)
{
  __shared__ __align__(16) char smem[32768];
  const bf16* A = (const bf16*)(ws + OFF_AO);
  const bf16* W = (const bf16*)(ws + OFF_WO);
  const int t = threadIdx.x;
  const int m0 = blockIdx.y * 128, n0 = blockIdx.x * 128;
  f32x4 acc[4][4] = {};
  gemm128_body(A, W, smem, m0, n0, t, acc);
  const int lane = t & 63, wid = t >> 6;
  const int wm = (wid >> 1) << 6, wn = (wid & 1) << 6;
  const int cl = lane & 15, rl = lane >> 4;
#pragma unroll
  for (int ni = 0; ni < 4; ++ni) {
    const int col = n0 + wn + ni * 16 + cl;
    const float bvv = bo[col];
#pragma unroll
    for (int mi = 0; mi < 4; ++mi)
#pragma unroll
      for (int r2 = 0; r2 < 4; ++r2) {
        const int row = m0 + wm + mi * 16 + rl * 4 + r2;
        outp[(size_t)row * Ee + col] = acc[mi][ni][r2] + bvv;
      }
  }
}

extern "C" void kernel_launch(void* const* d_in, const int* in_sizes, int n_in,
                              void* d_out, int out_size, void* d_ws, size_t ws_size,
                              hipStream_t stream) {
  (void)in_sizes; (void)n_in; (void)out_size; (void)ws_size;
  const float* queries = (const float*)d_in[0];
  const float* keys    = (const float*)d_in[1];
  const float* values  = (const float*)d_in[2];
  const float* Wq = (const float*)d_in[3];
  const float* bq = (const float*)d_in[4];
  const float* Wk = (const float*)d_in[5];
  const float* bk = (const float*)d_in[6];
  const float* Wv = (const float*)d_in[7];
  const float* bv = (const float*)d_in[8];
  const float* Wo = (const float*)d_in[9];
  const float* bo = (const float*)d_in[10];
  const int* indicator = (const int*)d_in[11];
  char* ws = (char*)d_ws;
  float* outp = (float*)d_out;

  convert_kernel<<<16384, 256, 0, stream>>>(queries, keys, values, Wq, Wk, Wv, Wo, ws);
  proj_gemm<<<dim3(8, 32, 3), 256, 0, stream>>>(ws, bq, bk, bv);
  attn_kernel<<<dim3(16, 32), 256, 0, stream>>>(ws, indicator);
  out_gemm<<<dim3(8, 32), 256, 0, stream>>>(ws, bo, outp);
}

// Round 2
// 253.937 us; speedup vs baseline: 1.1899x; 1.1899x over previous
//
#include <hip/hip_runtime.h>
#include <stdint.h>

#define Bb 2
#define Ss 2048
#define Ee 1024
#define Hh 16
#define Dd 64

typedef __bf16 bf16;
typedef __attribute__((ext_vector_type(8))) __bf16 bf16x8;
typedef __attribute__((ext_vector_type(4))) __bf16 bf16x4;
typedef __attribute__((ext_vector_type(4))) float f32x4;

#define MB (1u << 20)
// workspace layout (bf16 regions), total 64 MB
#define OFF_XQ 0u
#define OFF_XK (8u * MB)
#define OFF_XV (16u * MB)
#define OFF_WQ (24u * MB)
#define OFF_WK (26u * MB)
#define OFF_WV (28u * MB)
#define OFF_WO (30u * MB)
#define OFF_Q  (32u * MB)   // [B,H,S,D], prescaled by 1/8 via Wq,bq
#define OFF_K  (40u * MB)   // [B,H,S,D]
#define OFF_VT (48u * MB)   // [B,H,D,S]  (transposed V)
#define OFF_AO (56u * MB)   // [B*S, E] attention output

__device__ __forceinline__ void gll16(const void* g, void* lds) {
  __builtin_amdgcn_global_load_lds(
      (const __attribute__((address_space(1))) void*)g,
      (__attribute__((address_space(3))) void*)lds, 16, 0, 0);
}

__device__ __forceinline__ unsigned pkbf(float lo, float hi) {
  unsigned r;
  asm("v_cvt_pk_bf16_f32 %0, %1, %2" : "=v"(r) : "v"(lo), "v"(hi));
  return r;
}
#define PL32SWAP(a, b) asm("v_permlane32_swap_b32 %0, %1" : "+v"(a), "+v"(b))
#define PL16SWAP(a, b) asm("v_permlane16_swap_b32 %0, %1" : "+v"(a), "+v"(b))

// ---------------- convert fp32 -> bf16 (Wq scaled by 1/8) ----------------
__global__ __launch_bounds__(256) void convert_kernel(
    const float* __restrict__ q, const float* __restrict__ k, const float* __restrict__ v,
    const float* __restrict__ wq, const float* __restrict__ wk, const float* __restrict__ wv,
    const float* __restrict__ wo, char* __restrict__ ws)
{
  const unsigned i = blockIdx.x * 256u + threadIdx.x;  // float4 units, 4194304 total
  const float* src;
  bf16* dst;
  float scale = 1.0f;
  if (i < 3145728u) {                      // queries/keys/values: 1M float4 each
    const unsigned a = i >> 20, j = i & 1048575u;
    src = (a == 0 ? q : a == 1 ? k : v) + (size_t)j * 4;
    dst = (bf16*)(ws + (size_t)a * (8u * MB)) + (size_t)j * 4;
  } else {                                 // Wq,Wk,Wv,Wo: 256K float4 each
    const unsigned i2 = i - 3145728u;
    const unsigned a = i2 >> 18, j = i2 & 262143u;
    src = (a == 0 ? wq : a == 1 ? wk : a == 2 ? wv : wo) + (size_t)j * 4;
    dst = (bf16*)(ws + OFF_WQ + (size_t)a * (2u * MB)) + (size_t)j * 4;
    if (a == 0) scale = 0.125f;            // fold 1/sqrt(D) into Wq
  }
  const float4 f = *(const float4*)src;
  bf16x4 o;
  o[0] = (bf16)(f.x * scale);
  o[1] = (bf16)(f.y * scale);
  o[2] = (bf16)(f.z * scale);
  o[3] = (bf16)(f.w * scale);
  *(bf16x4*)dst = o;
}

// ---------------- shared 128x128x(K) bf16 GEMM body (C = A * W^T) ----------------
__device__ __forceinline__ void gemm128_body(
    const bf16* __restrict__ A, const bf16* __restrict__ W,
    char* smem, int m0, int n0, int t, f32x4 (&acc)[4][4])
{
  char* As = smem;
  char* Bs = smem + 16384;
  const int lane = t & 63;
  const int wid = t >> 6;
  const int wm = (wid >> 1) << 6;   // wave sub-tile origin
  const int wn = (wid & 1) << 6;
  for (int kt = 0; kt < 1024; kt += 64) {
    __syncthreads();
#pragma unroll
    for (int i = 0; i < 4; ++i) {
      const int L = i * 4096 + t * 16;        // linear LDS byte offset
      const int r = L >> 7;                   // tile row (128B rows)
      const int c = ((L >> 4) & 7) ^ (r & 7); // logical 16B chunk (pre-swizzled source)
      gll16(A + (size_t)(m0 + r) * 1024 + kt + c * 8, As + i * 4096 + wid * 1024);
      gll16(W + (size_t)(n0 + r) * 1024 + kt + c * 8, Bs + i * 4096 + wid * 1024);
    }
    __syncthreads();
#pragma unroll
    for (int ks = 0; ks < 2; ++ks) {
      bf16x8 af[4], bff[4];
#pragma unroll
      for (int mi = 0; mi < 4; ++mi) {
        const int r = wm + mi * 16 + (lane & 15);
        const int c = (ks * 4 + (lane >> 4)) ^ (r & 7);
        af[mi] = *(const bf16x8*)(As + r * 128 + c * 16);
      }
#pragma unroll
      for (int ni = 0; ni < 4; ++ni) {
        const int r = wn + ni * 16 + (lane & 15);
        const int c = (ks * 4 + (lane >> 4)) ^ (r & 7);
        bff[ni] = *(const bf16x8*)(Bs + r * 128 + c * 16);
      }
#pragma unroll
      for (int mi = 0; mi < 4; ++mi)
#pragma unroll
        for (int ni = 0; ni < 4; ++ni)
          acc[mi][ni] = __builtin_amdgcn_mfma_f32_16x16x32_bf16(af[mi], bff[ni], acc[mi][ni], 0, 0, 0);
    }
  }
}

// ---------------- fused Q/K/V projection (grid.z selects q/k/v) ----------------
__global__ __launch_bounds__(256) void proj_gemm(
    char* __restrict__ ws, const float* __restrict__ bq,
    const float* __restrict__ bk, const float* __restrict__ bv)
{
  __shared__ __align__(16) char smem[32768];
  const int zi = blockIdx.z;
  const bf16* A = (const bf16*)(ws + (zi == 0 ? OFF_XQ : zi == 1 ? OFF_XK : OFF_XV));
  const bf16* W = (const bf16*)(ws + (zi == 0 ? OFF_WQ : zi == 1 ? OFF_WK : OFF_WV));
  const float* bias = zi == 0 ? bq : zi == 1 ? bk : bv;
  bf16* outp = (bf16*)(ws + (zi == 0 ? OFF_Q : zi == 1 ? OFF_K : OFF_VT));
  const float bscale = (zi == 0) ? 0.125f : 1.0f;
  const int t = threadIdx.x;
  const int m0 = blockIdx.y * 128, n0 = blockIdx.x * 128;
  f32x4 acc[4][4] = {};
  gemm128_body(A, W, smem, m0, n0, t, acc);
  const int lane = t & 63, wid = t >> 6;
  const int wm = (wid >> 1) << 6, wn = (wid & 1) << 6;
  const int cl = lane & 15, rl = lane >> 4;
#pragma unroll
  for (int ni = 0; ni < 4; ++ni) {
    const int col = n0 + wn + ni * 16 + cl;
    const float bvv = bias[col] * bscale;
    const int h = col >> 6, d = col & 63;
#pragma unroll
    for (int mi = 0; mi < 4; ++mi) {
      const int row0 = m0 + wm + mi * 16 + rl * 4;  // token index (r2=0)
      const int b = row0 >> 11, s = row0 & 2047;
      if (zi == 2) {  // V stored transposed: [B,H,D,S]; 4 consecutive s -> one 8B store
        bf16x4 o;
#pragma unroll
        for (int r2 = 0; r2 < 4; ++r2) o[r2] = (bf16)(acc[mi][ni][r2] + bvv);
        *(bf16x4*)&outp[((size_t)((b * Hh + h) * Dd + d) * Ss) + s] = o;
      } else {        // Q/K: [B,H,S,D]
#pragma unroll
        for (int r2 = 0; r2 < 4; ++r2) {
          const float val = acc[mi][ni][r2] + bvv;
          outp[((size_t)((b * Hh + h) * Ss + s + r2) * Dd) + d] = (bf16)val;
        }
      }
    }
  }
}

// ---------------- attention: softmax(sigmoid(QK^T/8)) @ V ----------------
// grid: (S/64, B*H). 4 waves x 16 q-rows each. Swapped QK^T (St = K Q^T) so each
// lane owns one q column; P stays in registers (cvt_pk + permlane swaps build the
// PV B-fragment). sigmoid in (0,1) => no online max needed.
__global__ __launch_bounds__(256, 4) void attn_kernel(char* __restrict__ ws,
                                                      const int* __restrict__ indicator)
{
  __shared__ __align__(16) char smem[40960];
  char* Qs  = smem;            // [64 q][64 d] bf16, 128B rows, swz chunk^(r&7)  (8KB)
  char* Ks  = smem + 8192;     // [128 kv][64 d], 128B rows, swz (r&7)          (16KB)
  char* Vts = smem + 24576;    // [64 d][128 kv], 256B rows, swz (r&15)         (16KB)
  char* Os  = smem;            // output stage reuses Qs region (8KB)
  const int t = threadIdx.x, lane = t & 63, wid = t >> 6;
  const int g = lane >> 4, l15 = lane & 15;
  const int bh = blockIdx.y;
  const int q0 = blockIdx.x * 64;
  const bf16* Qg  = (const bf16*)(ws + OFF_Q)  + (size_t)bh * Ss * Dd;
  const bf16* Kg  = (const bf16*)(ws + OFF_K)  + (size_t)bh * Ss * Dd;
  const bf16* Vtg = (const bf16*)(ws + OFF_VT) + (size_t)bh * Ss * Dd;
  bf16* AO = (bf16*)(ws + OFF_AO);
  const int ind = *indicator;
  const float c1 = (ind != 0) ? 1.44269504f : -1.44269504f;

  // stage Q tile [64 q][64 d] (8KB)
#pragma unroll
  for (int i = 0; i < 2; ++i) {
    const int L = i * 4096 + t * 16;
    const int r = L >> 7;
    const int c = ((L >> 4) & 7) ^ (r & 7);
    gll16(Qg + (size_t)(q0 + r) * Dd + c * 8, Qs + i * 4096 + wid * 1024);
  }
  __syncthreads();
  // Q fragments (B operand of swapped mfma): lane holds col q = wid*16+l15, k = d
  bf16x8 qf[2];
#pragma unroll
  for (int ks = 0; ks < 2; ++ks) {
    const int r = wid * 16 + l15;
    const int c = (ks * 4 + g) ^ (r & 7);
    qf[ks] = *(const bf16x8*)(Qs + r * 128 + c * 16);
  }

  f32x4 acc_o[4] = {};   // Ot[d][q]: d = dblk*16 + g*4 + r2, q = l15 (wave-local)
  float psum = 0.0f;     // lane-local partial row sum over its kv subset

  for (int kt = 0; kt < Ss; kt += 128) {
    __syncthreads();
    // stage K tile [128 kv][64 d]
#pragma unroll
    for (int i = 0; i < 4; ++i) {
      const int L = i * 4096 + t * 16;
      const int r = L >> 7;
      const int c = ((L >> 4) & 7) ^ (r & 7);
      gll16(Kg + (size_t)(kt + r) * Dd + c * 8, Ks + i * 4096 + wid * 1024);
    }
    // stage Vt tile [64 d][128 kv]
#pragma unroll
    for (int i = 0; i < 4; ++i) {
      const int L = i * 4096 + t * 16;
      const int r = L >> 8;
      const int c = ((L >> 4) & 15) ^ (r & 15);
      gll16(Vtg + (size_t)r * Ss + kt + c * 8, Vts + i * 4096 + wid * 1024);
    }
    __syncthreads();

    // St = K Q^T : St[kv][q], kv = ni*16 + g*4 + r2, q = l15
    f32x4 st[8] = {};
#pragma unroll
    for (int ks = 0; ks < 2; ++ks) {
#pragma unroll
      for (int ni = 0; ni < 8; ++ni) {
        const int r = ni * 16 + l15;
        const int c = (ks * 4 + g) ^ (r & 7);
        const bf16x8 kf = *(const bf16x8*)(Ks + r * 128 + c * 16);
        st[ni] = __builtin_amdgcn_mfma_f32_16x16x32_bf16(kf, qf[ks], st[ni], 0, 0, 0);
      }
    }

    // per 32-kv block: p = exp(sigmoid(+/- s)); pack to bf16; permlane into PV B-frag
#pragma unroll
    for (int kb = 0; kb < 4; ++kb) {
      float p[2][4];
#pragma unroll
      for (int e = 0; e < 2; ++e)
#pragma unroll
        for (int r2 = 0; r2 < 4; ++r2) {
          const float sv = st[2 * kb + e][r2];
          const float ex = __builtin_amdgcn_exp2f(sv * c1);
          const float sig = __builtin_amdgcn_rcpf(1.0f + ex);
          const float pv = __builtin_amdgcn_exp2f(sig * 1.44269504f);
          psum += pv;
          p[e][r2] = pv;
        }
      unsigned E0 = pkbf(p[0][0], p[0][1]);
      unsigned E1 = pkbf(p[0][2], p[0][3]);
      unsigned O0 = pkbf(p[1][0], p[1][1]);
      unsigned O1 = pkbf(p[1][2], p[1][3]);
      // owner g_own=(kv%16)>>2 -> holder g_tgt=(kv%32)>>3: 32-swap then 16-swap
      PL32SWAP(E0, O0);
      PL16SWAP(E0, O0);  // E0 -> v0, O0 -> v2
      PL32SWAP(E1, O1);
      PL16SWAP(E1, O1);  // E1 -> v1, O1 -> v3
      union { unsigned u[4]; bf16x8 v; } pb;
      pb.u[0] = E0; pb.u[1] = E1; pb.u[2] = O0; pb.u[3] = O1;
      // Ot += Vt[dblk] * Pt
#pragma unroll
      for (int dblk = 0; dblk < 4; ++dblk) {
        const int r = dblk * 16 + l15;
        const int c = (kb * 4 + g) ^ (r & 15);
        const bf16x8 vf = *(const bf16x8*)(Vts + r * 256 + c * 16);
        acc_o[dblk] = __builtin_amdgcn_mfma_f32_16x16x32_bf16(vf, pb.v, acc_o[dblk], 0, 0, 0);
      }
    }
  }

  // full row sum: reduce across the 4 g-groups sharing q (lanes +-16, +-32)
  psum += __shfl_xor(psum, 16);
  psum += __shfl_xor(psum, 32);
  const float rinv = __builtin_amdgcn_rcpf(psum);

  // stage Ot -> Os [64 q][64 d] (swizzled), then coalesced global write
  __syncthreads();  // everyone done with Qs region
  {
    const int row = wid * 16 + l15;          // q within tile
#pragma unroll
    for (int dblk = 0; dblk < 4; ++dblk) {
      const unsigned w0 = pkbf(acc_o[dblk][0] * rinv, acc_o[dblk][1] * rinv);
      const unsigned w1 = pkbf(acc_o[dblk][2] * rinv, acc_o[dblk][3] * rinv);
      const int cc = dblk * 2 + (g >> 1);    // 16B chunk of d*2 bytes
      char* a = Os + row * 128 + (cc ^ (row & 7)) * 16 + (g & 1) * 8;
      *(uint2*)a = make_uint2(w0, w1);
    }
  }
  __syncthreads();
  const int b = bh >> 4, h = bh & 15;
#pragma unroll
  for (int i = 0; i < 2; ++i) {
    const int L = i * 4096 + t * 16;
    const int r = L >> 7;                    // q row
    const int cc = (L >> 4) & 7;             // logical chunk (d*2 bytes /16)
    const uint2 w = *(const uint2*)(Os + r * 128 + (cc ^ (r & 7)) * 16);
    const uint2 w2 = *(const uint2*)(Os + r * 128 + (cc ^ (r & 7)) * 16 + 8);
    bf16* dst = &AO[((size_t)(b * Ss + q0 + r) << 10) + h * 64 + cc * 8];
    *(uint2*)dst = w;
    *(uint2*)(dst + 4) = w2;
  }
}

// ---------------- output projection: d_out = AO @ Wo^T + bo (fp32 out) ----------------
__global__ __launch_bounds__(256) void out_gemm(char* __restrict__ ws,
                                                const float* __restrict__ bo,
                                                float* __restrict__ outp)
{
  __shared__ __align__(16) char smem[32768];
  const bf16* A = (const bf16*)(ws + OFF_AO);
  const bf16* W = (const bf16*)(ws + OFF_WO);
  const int t = threadIdx.x;
  const int m0 = blockIdx.y * 128, n0 = blockIdx.x * 128;
  f32x4 acc[4][4] = {};
  gemm128_body(A, W, smem, m0, n0, t, acc);
  const int lane = t & 63, wid = t >> 6;
  const int wm = (wid >> 1) << 6, wn = (wid & 1) << 6;
  const int cl = lane & 15, rl = lane >> 4;
#pragma unroll
  for (int ni = 0; ni < 4; ++ni) {
    const int col = n0 + wn + ni * 16 + cl;
    const float bvv = bo[col];
#pragma unroll
    for (int mi = 0; mi < 4; ++mi)
#pragma unroll
      for (int r2 = 0; r2 < 4; ++r2) {
        const int row = m0 + wm + mi * 16 + rl * 4 + r2;
        outp[(size_t)row * Ee + col] = acc[mi][ni][r2] + bvv;
      }
  }
}

extern "C" void kernel_launch(void* const* d_in, const int* in_sizes, int n_in,
                              void* d_out, int out_size, void* d_ws, size_t ws_size,
                              hipStream_t stream) {
  (void)in_sizes; (void)n_in; (void)out_size; (void)ws_size;
  const float* queries = (const float*)d_in[0];
  const float* keys    = (const float*)d_in[1];
  const float* values  = (const float*)d_in[2];
  const float* Wq = (const float*)d_in[3];
  const float* bq = (const float*)d_in[4];
  const float* Wk = (const float*)d_in[5];
  const float* bk = (const float*)d_in[6];
  const float* Wv = (const float*)d_in[7];
  const float* bv = (const float*)d_in[8];
  const float* Wo = (const float*)d_in[9];
  const float* bo = (const float*)d_in[10];
  const int* indicator = (const int*)d_in[11];
  char* ws = (char*)d_ws;
  float* outp = (float*)d_out;

  convert_kernel<<<16384, 256, 0, stream>>>(queries, keys, values, Wq, Wk, Wv, Wo, ws);
  proj_gemm<<<dim3(8, 32, 3), 256, 0, stream>>>(ws, bq, bk, bv);
  attn_kernel<<<dim3(32, 32), 256, 0, stream>>>(ws, indicator);
  out_gemm<<<dim3(8, 32), 256, 0, stream>>>(ws, bo, outp);
}

// Round 3
// 235.944 us; speedup vs baseline: 1.2807x; 1.0763x over previous
//
#include <hip/hip_runtime.h>
#include <stdint.h>

#define Bb 2
#define Ss 2048
#define Ee 1024
#define Hh 16
#define Dd 64

typedef __bf16 bf16;
typedef __attribute__((ext_vector_type(8))) __bf16 bf16x8;
typedef __attribute__((ext_vector_type(4))) __bf16 bf16x4;
typedef __attribute__((ext_vector_type(4))) float f32x4;

#define MB (1u << 20)
// workspace layout (bf16 regions), total 64 MB
#define OFF_XQ 0u
#define OFF_XK (8u * MB)
#define OFF_XV (16u * MB)
#define OFF_WQ (24u * MB)
#define OFF_WK (26u * MB)
#define OFF_WV (28u * MB)
#define OFF_WO (30u * MB)
#define OFF_Q  (32u * MB)   // [B,H,S,D], prescaled by c1/8 (c1 = +-log2e per indicator)
#define OFF_K  (40u * MB)   // [B,H,S,D]
#define OFF_VT (48u * MB)   // [B,H,D,S]  (transposed V)
#define OFF_AO (56u * MB)   // [B*S, E] attention output

__device__ __forceinline__ void gll16(const void* g, void* lds) {
  __builtin_amdgcn_global_load_lds(
      (const __attribute__((address_space(1))) void*)g,
      (__attribute__((address_space(3))) void*)lds, 16, 0, 0);
}

__device__ __forceinline__ unsigned pkbf(float lo, float hi) {
  unsigned r;
  asm("v_cvt_pk_bf16_f32 %0, %1, %2" : "=v"(r) : "v"(lo), "v"(hi));
  return r;
}
#define PL32SWAP(a, b) asm("v_permlane32_swap_b32 %0, %1" : "+v"(a), "+v"(b))
#define PL16SWAP(a, b) asm("v_permlane16_swap_b32 %0, %1" : "+v"(a), "+v"(b))

// ---------------- convert fp32 -> bf16 (Wq scaled by c1/8) ----------------
__global__ __launch_bounds__(256) void convert_kernel(
    const float* __restrict__ q, const float* __restrict__ k, const float* __restrict__ v,
    const float* __restrict__ wq, const float* __restrict__ wk, const float* __restrict__ wv,
    const float* __restrict__ wo, const int* __restrict__ ind, char* __restrict__ ws)
{
  const unsigned i = blockIdx.x * 256u + threadIdx.x;  // float4 units, 4194304 total
  const float* src;
  bf16* dst;
  float scale = 1.0f;
  if (i < 3145728u) {                      // queries/keys/values: 1M float4 each
    const unsigned a = i >> 20, j = i & 1048575u;
    src = (a == 0 ? q : a == 1 ? k : v) + (size_t)j * 4;
    dst = (bf16*)(ws + (size_t)a * (8u * MB)) + (size_t)j * 4;
  } else {                                 // Wq,Wk,Wv,Wo: 256K float4 each
    const unsigned i2 = i - 3145728u;
    const unsigned a = i2 >> 18, j = i2 & 262143u;
    src = (a == 0 ? wq : a == 1 ? wk : a == 2 ? wv : wo) + (size_t)j * 4;
    dst = (bf16*)(ws + OFF_WQ + (size_t)a * (2u * MB)) + (size_t)j * 4;
    if (a == 0) {                          // fold 1/sqrt(D) and +-log2e into Wq
      const float c1v = (*ind != 0) ? 1.442695041f : -1.442695041f;
      scale = 0.125f * c1v;
    }
  }
  const float4 f = *(const float4*)src;
  bf16x4 o;
  o[0] = (bf16)(f.x * scale);
  o[1] = (bf16)(f.y * scale);
  o[2] = (bf16)(f.z * scale);
  o[3] = (bf16)(f.w * scale);
  *(bf16x4*)dst = o;
}

// ---------------- shared 128x128x(K) bf16 GEMM body (C = A * W^T) ----------------
__device__ __forceinline__ void gemm128_body(
    const bf16* __restrict__ A, const bf16* __restrict__ W,
    char* smem, int m0, int n0, int t, f32x4 (&acc)[4][4])
{
  char* As = smem;
  char* Bs = smem + 16384;
  const int lane = t & 63;
  const int wid = t >> 6;
  const int wm = (wid >> 1) << 6;   // wave sub-tile origin
  const int wn = (wid & 1) << 6;
  for (int kt = 0; kt < 1024; kt += 64) {
    __syncthreads();
#pragma unroll
    for (int i = 0; i < 4; ++i) {
      const int L = i * 4096 + t * 16;        // linear LDS byte offset
      const int r = L >> 7;                   // tile row (128B rows)
      const int c = ((L >> 4) & 7) ^ (r & 7); // logical 16B chunk (pre-swizzled source)
      gll16(A + (size_t)(m0 + r) * 1024 + kt + c * 8, As + i * 4096 + wid * 1024);
      gll16(W + (size_t)(n0 + r) * 1024 + kt + c * 8, Bs + i * 4096 + wid * 1024);
    }
    __syncthreads();
#pragma unroll
    for (int ks = 0; ks < 2; ++ks) {
      bf16x8 af[4], bff[4];
#pragma unroll
      for (int mi = 0; mi < 4; ++mi) {
        const int r = wm + mi * 16 + (lane & 15);
        const int c = (ks * 4 + (lane >> 4)) ^ (r & 7);
        af[mi] = *(const bf16x8*)(As + r * 128 + c * 16);
      }
#pragma unroll
      for (int ni = 0; ni < 4; ++ni) {
        const int r = wn + ni * 16 + (lane & 15);
        const int c = (ks * 4 + (lane >> 4)) ^ (r & 7);
        bff[ni] = *(const bf16x8*)(Bs + r * 128 + c * 16);
      }
      __builtin_amdgcn_s_setprio(1);
#pragma unroll
      for (int mi = 0; mi < 4; ++mi)
#pragma unroll
        for (int ni = 0; ni < 4; ++ni)
          acc[mi][ni] = __builtin_amdgcn_mfma_f32_16x16x32_bf16(af[mi], bff[ni], acc[mi][ni], 0, 0, 0);
      __builtin_amdgcn_s_setprio(0);
    }
  }
}

// ---------------- fused Q/K/V projection (grid.z selects q/k/v) ----------------
__global__ __launch_bounds__(256) void proj_gemm(
    char* __restrict__ ws, const float* __restrict__ bq,
    const float* __restrict__ bk, const float* __restrict__ bv,
    const int* __restrict__ ind)
{
  __shared__ __align__(16) char smem[32768];
  const int zi = blockIdx.z;
  const bf16* A = (const bf16*)(ws + (zi == 0 ? OFF_XQ : zi == 1 ? OFF_XK : OFF_XV));
  const bf16* W = (const bf16*)(ws + (zi == 0 ? OFF_WQ : zi == 1 ? OFF_WK : OFF_WV));
  const float* bias = zi == 0 ? bq : zi == 1 ? bk : bv;
  bf16* outp = (bf16*)(ws + (zi == 0 ? OFF_Q : zi == 1 ? OFF_K : OFF_VT));
  const float c1v = (*ind != 0) ? 1.442695041f : -1.442695041f;
  const float bscale = (zi == 0) ? 0.125f * c1v : 1.0f;
  const int t = threadIdx.x;
  const int m0 = blockIdx.y * 128, n0 = blockIdx.x * 128;
  f32x4 acc[4][4] = {};
  gemm128_body(A, W, smem, m0, n0, t, acc);
  const int lane = t & 63, wid = t >> 6;
  const int wm = (wid >> 1) << 6, wn = (wid & 1) << 6;
  const int cl = lane & 15, rl = lane >> 4;
#pragma unroll
  for (int ni = 0; ni < 4; ++ni) {
    const int col = n0 + wn + ni * 16 + cl;
    const float bvv = bias[col] * bscale;
    const int h = col >> 6, d = col & 63;
#pragma unroll
    for (int mi = 0; mi < 4; ++mi) {
      const int row0 = m0 + wm + mi * 16 + rl * 4;  // token index (r2=0)
      const int b = row0 >> 11, s = row0 & 2047;
      if (zi == 2) {  // V stored transposed: [B,H,D,S]; 4 consecutive s -> one 8B store
        bf16x4 o;
#pragma unroll
        for (int r2 = 0; r2 < 4; ++r2) o[r2] = (bf16)(acc[mi][ni][r2] + bvv);
        *(bf16x4*)&outp[((size_t)((b * Hh + h) * Dd + d) * Ss) + s] = o;
      } else {        // Q/K: [B,H,S,D]
#pragma unroll
        for (int r2 = 0; r2 < 4; ++r2) {
          const float val = acc[mi][ni][r2] + bvv;
          outp[((size_t)((b * Hh + h) * Ss + s + r2) * Dd) + d] = (bf16)val;
        }
      }
    }
  }
}

// ---------------- attention: softmax(sigmoid(QK^T/8)) @ V ----------------
// grid: (S/128, B*H). 4 waves x 32 q-rows each. Swapped QK^T; P in registers.
// Scores arrive as c1*s (c1 folded into Q); acc init -log2(log2e) so
// p = exp2(rcp(ln2 + exp2(st))). Row sums via all-ones-A MFMA.
__global__ __launch_bounds__(256, 2) void attn_kernel(char* __restrict__ ws)
{
  __shared__ __align__(16) char smem[49152];
  char* Qs  = smem;            // [128 q][64 d] bf16, 128B rows, swz chunk^(r&7) (16KB)
  char* Ks  = smem + 16384;    // [128 kv][64 d], 128B rows, swz (r&7)           (16KB)
  char* Vts = smem + 32768;    // [64 d][128 kv], 256B rows, swz (r&15)          (16KB)
  char* Os  = smem;            // output stage reuses Qs region (16KB)
  const int t = threadIdx.x, lane = t & 63, wid = t >> 6;
  const int g = lane >> 4, l15 = lane & 15;
  const int bh = blockIdx.y;
  const int q0 = blockIdx.x * 128;
  const bf16* Qg  = (const bf16*)(ws + OFF_Q)  + (size_t)bh * Ss * Dd;
  const bf16* Kg  = (const bf16*)(ws + OFF_K)  + (size_t)bh * Ss * Dd;
  const bf16* Vtg = (const bf16*)(ws + OFF_VT) + (size_t)bh * Ss * Dd;
  bf16* AO = (bf16*)(ws + OFF_AO);

  // stage Q tile [128 q][64 d]
#pragma unroll
  for (int i = 0; i < 4; ++i) {
    const int L = i * 4096 + t * 16;
    const int r = L >> 7;
    const int c = ((L >> 4) & 7) ^ (r & 7);
    gll16(Qg + (size_t)(q0 + r) * Dd + c * 8, Qs + i * 4096 + wid * 1024);
  }
  __syncthreads();
  // Q fragments (B operand): wave covers q rows [wid*32, wid*32+32)
  bf16x8 qf[2][2];
#pragma unroll
  for (int qh = 0; qh < 2; ++qh)
#pragma unroll
    for (int ks = 0; ks < 2; ++ks) {
      const int r = wid * 32 + qh * 16 + l15;
      const int c = (ks * 4 + g) ^ (r & 7);
      qf[qh][ks] = *(const bf16x8*)(Qs + r * 128 + c * 16);
    }

  f32x4 acc_o[2][4] = {};   // [qh][dblk]: Ot[d][q], d = dblk*16+g*4+r2, q = l15
  f32x4 acc_sum[2] = {};    // row sums via ones-MFMA (all lanes get full sum for q=l15)
  union { unsigned u[4]; bf16x8 v; } ones_;
#pragma unroll
  for (int j = 0; j < 4; ++j) ones_.u[j] = 0x3F803F80u;  // bf16 1.0 pairs

  for (int kt = 0; kt < Ss; kt += 128) {
    __syncthreads();
    // stage K tile [128 kv][64 d]
#pragma unroll
    for (int i = 0; i < 4; ++i) {
      const int L = i * 4096 + t * 16;
      const int r = L >> 7;
      const int c = ((L >> 4) & 7) ^ (r & 7);
      gll16(Kg + (size_t)(kt + r) * Dd + c * 8, Ks + i * 4096 + wid * 1024);
    }
    // stage Vt tile [64 d][128 kv]
#pragma unroll
    for (int i = 0; i < 4; ++i) {
      const int L = i * 4096 + t * 16;
      const int r = L >> 8;
      const int c = ((L >> 4) & 15) ^ (r & 15);
      gll16(Vtg + (size_t)r * Ss + kt + c * 8, Vts + i * 4096 + wid * 1024);
    }
    __syncthreads();

    // St = K Q^T : St[kv][q], kv = ni*16 + g*4 + r2, q = l15; init -log2(log2e)
    f32x4 st[2][8];
#pragma unroll
    for (int qh = 0; qh < 2; ++qh)
#pragma unroll
      for (int ni = 0; ni < 8; ++ni)
        st[qh][ni] = (f32x4){-0.52876637f, -0.52876637f, -0.52876637f, -0.52876637f};
    __builtin_amdgcn_s_setprio(1);
#pragma unroll
    for (int ks = 0; ks < 2; ++ks) {
#pragma unroll
      for (int ni = 0; ni < 8; ++ni) {
        const int r = ni * 16 + l15;
        const int c = (ks * 4 + g) ^ (r & 7);
        const bf16x8 kf = *(const bf16x8*)(Ks + r * 128 + c * 16);
        st[0][ni] = __builtin_amdgcn_mfma_f32_16x16x32_bf16(kf, qf[0][ks], st[0][ni], 0, 0, 0);
        st[1][ni] = __builtin_amdgcn_mfma_f32_16x16x32_bf16(kf, qf[1][ks], st[1][ni], 0, 0, 0);
      }
    }
    __builtin_amdgcn_s_setprio(0);

    // per 32-kv block: p = exp2(rcp(ln2 + exp2(st))); pack; permlane into PV B-frag
#pragma unroll
    for (int kb = 0; kb < 4; ++kb) {
      union { unsigned u[4]; bf16x8 v; } pb[2];
#pragma unroll
      for (int qh = 0; qh < 2; ++qh) {
        float p[2][4];
#pragma unroll
        for (int e = 0; e < 2; ++e)
#pragma unroll
          for (int r2 = 0; r2 < 4; ++r2) {
            const float ex = __builtin_amdgcn_exp2f(st[qh][2 * kb + e][r2]);
            const float tt = __builtin_amdgcn_rcpf(0.69314718f + ex);
            p[e][r2] = __builtin_amdgcn_exp2f(tt);
          }
        unsigned E0 = pkbf(p[0][0], p[0][1]);
        unsigned E1 = pkbf(p[0][2], p[0][3]);
        unsigned O0 = pkbf(p[1][0], p[1][1]);
        unsigned O1 = pkbf(p[1][2], p[1][3]);
        PL32SWAP(E0, O0);
        PL16SWAP(E0, O0);
        PL32SWAP(E1, O1);
        PL16SWAP(E1, O1);
        pb[qh].u[0] = E0; pb[qh].u[1] = E1; pb[qh].u[2] = O0; pb[qh].u[3] = O1;
      }
      __builtin_amdgcn_s_setprio(1);
#pragma unroll
      for (int dblk = 0; dblk < 4; ++dblk) {
        const int r = dblk * 16 + l15;
        const int c = (kb * 4 + g) ^ (r & 15);
        const bf16x8 vf = *(const bf16x8*)(Vts + r * 256 + c * 16);
        acc_o[0][dblk] = __builtin_amdgcn_mfma_f32_16x16x32_bf16(vf, pb[0].v, acc_o[0][dblk], 0, 0, 0);
        acc_o[1][dblk] = __builtin_amdgcn_mfma_f32_16x16x32_bf16(vf, pb[1].v, acc_o[1][dblk], 0, 0, 0);
      }
      acc_sum[0] = __builtin_amdgcn_mfma_f32_16x16x32_bf16(ones_.v, pb[0].v, acc_sum[0], 0, 0, 0);
      acc_sum[1] = __builtin_amdgcn_mfma_f32_16x16x32_bf16(ones_.v, pb[1].v, acc_sum[1], 0, 0, 0);
      __builtin_amdgcn_s_setprio(0);
    }
  }

  const float rinv[2] = {__builtin_amdgcn_rcpf(acc_sum[0][0]),
                         __builtin_amdgcn_rcpf(acc_sum[1][0])};

  // stage Ot -> Os [128 q][64 d] (swizzled), then coalesced global write
  __syncthreads();  // everyone done reading Qs region
#pragma unroll
  for (int qh = 0; qh < 2; ++qh) {
    const int row = wid * 32 + qh * 16 + l15;
#pragma unroll
    for (int dblk = 0; dblk < 4; ++dblk) {
      const unsigned w0 = pkbf(acc_o[qh][dblk][0] * rinv[qh], acc_o[qh][dblk][1] * rinv[qh]);
      const unsigned w1 = pkbf(acc_o[qh][dblk][2] * rinv[qh], acc_o[qh][dblk][3] * rinv[qh]);
      const int cc = dblk * 2 + (g >> 1);
      char* a = Os + row * 128 + (cc ^ (row & 7)) * 16 + (g & 1) * 8;
      *(uint2*)a = make_uint2(w0, w1);
    }
  }
  __syncthreads();
  const int b = bh >> 4, h = bh & 15;
#pragma unroll
  for (int i = 0; i < 4; ++i) {
    const int L = i * 4096 + t * 16;
    const int r = L >> 7;                    // q row
    const int cc = (L >> 4) & 7;             // logical chunk (d*2 bytes /16)
    const uint4 w = *(const uint4*)(Os + r * 128 + (cc ^ (r & 7)) * 16);
    *(uint4*)&AO[((size_t)(b * Ss + q0 + r) << 10) + h * 64 + cc * 8] = w;
  }
}

// ---------------- output projection: d_out = AO @ Wo^T + bo (fp32 out) ----------------
// 128x64 tiles -> 512 blocks (2/CU) for TLP across the barrier drain.
__global__ __launch_bounds__(256) void out_gemm(char* __restrict__ ws,
                                                const float* __restrict__ bo,
                                                float* __restrict__ outp)
{
  __shared__ __align__(16) char smem[24576];
  char* As = smem;           // [128][64] bf16 (16KB)
  char* Bs = smem + 16384;   // [64][64] bf16 (8KB)
  const bf16* A = (const bf16*)(ws + OFF_AO);
  const bf16* W = (const bf16*)(ws + OFF_WO);
  const int t = threadIdx.x, lane = t & 63, wid = t >> 6;
  const int l15 = lane & 15, g = lane >> 4;
  const int m0 = blockIdx.y * 128, n0 = blockIdx.x * 64;
  const int wm = (wid >> 1) << 6;   // 2 waves M x 2 waves N
  const int wn = (wid & 1) << 5;
  f32x4 acc[4][2] = {};
  for (int kt = 0; kt < 1024; kt += 64) {
    __syncthreads();
#pragma unroll
    for (int i = 0; i < 4; ++i) {
      const int L = i * 4096 + t * 16;
      const int r = L >> 7;
      const int c = ((L >> 4) & 7) ^ (r & 7);
      gll16(A + (size_t)(m0 + r) * 1024 + kt + c * 8, As + i * 4096 + wid * 1024);
    }
#pragma unroll
    for (int i = 0; i < 2; ++i) {
      const int L = i * 4096 + t * 16;
      const int r = L >> 7;
      const int c = ((L >> 4) & 7) ^ (r & 7);
      gll16(W + (size_t)(n0 + r) * 1024 + kt + c * 8, Bs + i * 4096 + wid * 1024);
    }
    __syncthreads();
#pragma unroll
    for (int ks = 0; ks < 2; ++ks) {
      bf16x8 af[4], bff[2];
#pragma unroll
      for (int mi = 0; mi < 4; ++mi) {
        const int r = wm + mi * 16 + l15;
        const int c = (ks * 4 + g) ^ (r & 7);
        af[mi] = *(const bf16x8*)(As + r * 128 + c * 16);
      }
#pragma unroll
      for (int ni = 0; ni < 2; ++ni) {
        const int r = wn + ni * 16 + l15;
        const int c = (ks * 4 + g) ^ (r & 7);
        bff[ni] = *(const bf16x8*)(Bs + r * 128 + c * 16);
      }
      __builtin_amdgcn_s_setprio(1);
#pragma unroll
      for (int mi = 0; mi < 4; ++mi)
#pragma unroll
        for (int ni = 0; ni < 2; ++ni)
          acc[mi][ni] = __builtin_amdgcn_mfma_f32_16x16x32_bf16(af[mi], bff[ni], acc[mi][ni], 0, 0, 0);
      __builtin_amdgcn_s_setprio(0);
    }
  }
#pragma unroll
  for (int ni = 0; ni < 2; ++ni) {
    const int col = n0 + wn + ni * 16 + l15;
    const float bvv = bo[col];
#pragma unroll
    for (int mi = 0; mi < 4; ++mi)
#pragma unroll
      for (int r2 = 0; r2 < 4; ++r2) {
        const int row = m0 + wm + mi * 16 + g * 4 + r2;
        outp[(size_t)row * Ee + col] = acc[mi][ni][r2] + bvv;
      }
  }
}

extern "C" void kernel_launch(void* const* d_in, const int* in_sizes, int n_in,
                              void* d_out, int out_size, void* d_ws, size_t ws_size,
                              hipStream_t stream) {
  (void)in_sizes; (void)n_in; (void)out_size; (void)ws_size;
  const float* queries = (const float*)d_in[0];
  const float* keys    = (const float*)d_in[1];
  const float* values  = (const float*)d_in[2];
  const float* Wq = (const float*)d_in[3];
  const float* bq = (const float*)d_in[4];
  const float* Wk = (const float*)d_in[5];
  const float* bk = (const float*)d_in[6];
  const float* Wv = (const float*)d_in[7];
  const float* bv = (const float*)d_in[8];
  const float* Wo = (const float*)d_in[9];
  const float* bo = (const float*)d_in[10];
  const int* indicator = (const int*)d_in[11];
  char* ws = (char*)d_ws;
  float* outp = (float*)d_out;

  convert_kernel<<<16384, 256, 0, stream>>>(queries, keys, values, Wq, Wk, Wv, Wo, indicator, ws);
  proj_gemm<<<dim3(8, 32, 3), 256, 0, stream>>>(ws, bq, bk, bv, indicator);
  attn_kernel<<<dim3(16, 32), 256, 0, stream>>>(ws);
  out_gemm<<<dim3(16, 32), 256, 0, stream>>>(ws, bo, outp);
}